// Round 10
// baseline (185.018 us; speedup 1.0000x reference)
//
#include <hip/hip_runtime.h>
#include <hip/hip_bf16.h>

#define BB 4
#define NN 200
#define HH 300
#define NCH 10            // k-chunks of 32 (K padded to 320)
#define GHF 10            // g-frags of 16 per g-half (G padded to 320)
#define BM 64             // rows per block

typedef __attribute__((ext_vector_type(8))) short short8;
typedef __attribute__((ext_vector_type(4))) float float4v;

static __device__ __forceinline__ ushort f2bf(float x) {
    union { float f; uint u; } v; v.f = x;
    uint r = v.u + 0x7FFFu + ((v.u >> 16) & 1u);  // RNE
    return (ushort)(r >> 16);
}

// 8 f32 -> 8 bf16 (RNE) via v_cvt_pk_bf16_f32
static __device__ __forceinline__ short8 pack8_cvt(float4v a, float4v b) {
    uint u0, u1, u2, u3;
    asm("v_cvt_pk_bf16_f32 %0, %1, %2" : "=v"(u0) : "v"(a[0]), "v"(a[1]));
    asm("v_cvt_pk_bf16_f32 %0, %1, %2" : "=v"(u1) : "v"(a[2]), "v"(a[3]));
    asm("v_cvt_pk_bf16_f32 %0, %1, %2" : "=v"(u2) : "v"(b[0]), "v"(b[1]));
    asm("v_cvt_pk_bf16_f32 %0, %1, %2" : "=v"(u3) : "v"(b[2]), "v"(b[3]));
    union { uint u[4]; short8 s; } r;
    r.u[0] = u0; r.u[1] = u1; r.u[2] = u2; r.u[3] = u3;
    return r.s;
}

static __device__ __forceinline__ void gload_lds16(const void* g, void* l) {
    __builtin_amdgcn_global_load_lds(
        (const __attribute__((address_space(1))) unsigned int*)g,
        (__attribute__((address_space(3))) unsigned int*)l, 16, 0, 0);
}

// Pack U_w (g,h) f32 -> bf16 frag order, g-half-major:
// off = ((gh*NCH + ks)*GHF + fh)*1024B ; elem: g=(gh*GHF+fh)*16+(lane&15), h=ks*32+(lane>>4)*8+j
__global__ void pack_u(const float* __restrict__ Uw, ushort* __restrict__ Bp) {
    int idx = blockIdx.x * 256 + threadIdx.x;
    if (idx >= 2 * NCH * GHF * 64) return;
    int lane = idx & 63;
    int rem = idx >> 6;                 // 0..199: ((gh*NCH+ks)*GHF+fh)
    int fh = rem % GHF;
    int ks = (rem / GHF) % NCH;
    int gh = rem / (GHF * NCH);
    int g = (gh * GHF + fh) * 16 + (lane & 15);
    int h0 = ks * 32 + (lane >> 4) * 8;
    ushort v[8];
#pragma unroll
    for (int j = 0; j < 8; ++j) {
        int h = h0 + j;
        v[j] = (g < HH && h < HH) ? f2bf(Uw[g * HH + h]) : (ushort)0;
    }
    *reinterpret_cast<short8*>(Bp + (size_t)idx * 8) = *reinterpret_cast<const short8*>(v);
}

// Vx[b,n,g] = sum_h x[b,n,h]*Vw[g,h] + Vb[g] + 0.5*Ub[g]   (Ub folded)
__global__ void vx_kernel(const float* __restrict__ x, const float* __restrict__ Vw,
                          const float* __restrict__ Vb, const float* __restrict__ Ub,
                          float* __restrict__ Vx) {
    __shared__ float xs[HH];
    int row = blockIdx.x;
    const float* xr = x + (size_t)row * HH;
    for (int h = threadIdx.x; h < HH; h += 256) xs[h] = xr[h];
    __syncthreads();
    for (int g = threadIdx.x; g < HH; g += 256) {
        const float4* wr = reinterpret_cast<const float4*>(Vw + (size_t)g * HH);
        const float4* xv = reinterpret_cast<const float4*>(xs);
        float s0 = 0.f, s1 = 0.f, s2 = 0.f, s3 = 0.f;
#pragma unroll 5
        for (int k = 0; k < HH / 4; ++k) {
            float4 w = wr[k];
            float4 xx = xv[k];
            s0 += w.x * xx.x; s1 += w.y * xx.y; s2 += w.z * xx.z; s3 += w.w * xx.w;
        }
        Vx[(size_t)row * HH + g] = Vb[g] + 0.5f * Ub[g] + s0 + s1 + s2 + s3;
    }
}

// BM=64 x G-half (160), 256 thr (4 waves x 16 rows), BK=32, 10 chunks, 28 KB LDS
// -> 5 independent blocks/CU (20 waves). A: global->reg->cvt->ds_write bf16 (3-deep
// reg prefetch). B: gload_lds (10 KB/chunk), double-buffered. One barrier + counted
// WAITV(2) per chunk. Twin blocks (gh=0/1) adjacent for L3 reuse of e rows.
__launch_bounds__(256, 5)
__global__ void gemm_kernel(const float* __restrict__ e, const ushort* __restrict__ Bp,
                            const float* __restrict__ Vx, float* __restrict__ out) {
    __shared__ __align__(16) ushort Alds[2][BM * 32];      // 2 x 4 KB (bf16)
    __shared__ __align__(16) ushort Blds[2][GHF * 512];    // 2 x 10 KB
    const int tid = threadIdx.x;
    const int w = tid >> 6, l = tid & 63;
    const int r = l & 15, q = l >> 4;
    const int gh = blockIdx.x & 1;
    const int m0 = (blockIdx.x >> 1) * BM;
    const int arow = tid >> 2;            // 0..63: A row this thread stages
    const int acg = tid & 3;              // col-group (8 f32) within BK=32
    const float* rowp = e + (size_t)(m0 + arow) * HH;
    const int awidx = ((arow >> 4) * 64 + (arow & 15) + acg * 16) * 8;  // frag slot
    const char* bbase = (const char*)Bp + (size_t)gh * (NCH * GHF * 1024);

    float4v s0a, s0b, s1a, s1b, s2a, s2b;   // 3 rotating A reg sets

    float4v acc[GHF];
#pragma unroll
    for (int f = 0; f < GHF; ++f) acc[f] = (float4v){0.f, 0.f, 0.f, 0.f};

#define LOAD_A(K_, S_) do {                                                     \
        int c0_ = (K_) * 32 + acg * 8;                                          \
        const float* p0_ = (c0_ + 4 <= HH) ? rowp + c0_ : e;                    \
        const float* p1_ = (c0_ + 8 <= HH) ? rowp + c0_ + 4 : e;                \
        S_##a = *reinterpret_cast<const float4v*>(p0_);                         \
        S_##b = *reinterpret_cast<const float4v*>(p1_);                         \
    } while (0)

#define WRITE_A(K_, S_, P_) do {                                                \
        short8 w_ = pack8_cvt(S_##a, S_##b);                                    \
        if ((K_) == 9) {                                                        \
            _Pragma("unroll")                                                   \
            for (int j_ = 0; j_ < 8; ++j_)                                      \
                if (288 + acg * 8 + j_ >= HH) w_[j_] = 0;                       \
        }                                                                       \
        *reinterpret_cast<short8*>(&Alds[P_][awidx]) = w_;                      \
    } while (0)

    // 10 KB B chunk: 2 full 4-KB rounds + one half round (waves 0,1 only; wave-uniform)
#define ISSUE_B(K_, P_) do {                                                    \
        const char* bs_ = bbase + (size_t)(K_) * (GHF * 1024);                  \
        char* bd_ = (char*)&Blds[P_][0];                                        \
        gload_lds16(bs_ + tid * 16,        bd_ + tid * 16);                     \
        gload_lds16(bs_ + 4096 + tid * 16, bd_ + 4096 + tid * 16);              \
        if (tid < 128)                                                          \
            gload_lds16(bs_ + 8192 + tid * 16, bd_ + 8192 + tid * 16);          \
    } while (0)

#define COMPUTE(P_) do {                                                        \
        short8 fa_ = *reinterpret_cast<const short8*>(&Alds[P_][(w * 64 + l) * 8]); \
        const ushort* bb_ = &Blds[P_][l * 8];                                   \
        _Pragma("unroll")                                                       \
        for (int f_ = 0; f_ < GHF; ++f_) {                                      \
            short8 bf_ = *reinterpret_cast<const short8*>(bb_ + f_ * 512);      \
            acc[f_] = __builtin_amdgcn_mfma_f32_16x16x32_bf16(bf_, fa_, acc[f_], 0, 0, 0); \
        }                                                                       \
    } while (0)

#define WAITV(N_) do {                                                          \
        __builtin_amdgcn_sched_barrier(0);                                      \
        asm volatile("s_waitcnt vmcnt(" #N_ ")" ::: "memory");                  \
        __builtin_amdgcn_sched_barrier(0);                                      \
    } while (0)

#define ENDPHASE() do {                                                         \
        asm volatile("s_waitcnt lgkmcnt(0)" ::: "memory");                      \
        __builtin_amdgcn_s_barrier();                                           \
        __builtin_amdgcn_sched_barrier(0);                                      \
    } while (0)

    // ---- prologue: stage chunk0 (A+B), prefetch A1,A2 regs ----
    LOAD_A(0, s0); ISSUE_B(0, 0); LOAD_A(1, s1); LOAD_A(2, s2);
    WRITE_A(0, s0, 0);          // reg-dep forces s0 arrival
    WAITV(2);                   // B0 (and A1) done; A2 may stay in flight
    ENDPHASE();

    // ---- 10 phases: 1 barrier each, counted vmcnt ----
    WRITE_A(1, s1, 1); ISSUE_B(1, 1); LOAD_A(3, s0); COMPUTE(0); WAITV(2); ENDPHASE();
    WRITE_A(2, s2, 0); ISSUE_B(2, 0); LOAD_A(4, s1); COMPUTE(1); WAITV(2); ENDPHASE();
    WRITE_A(3, s0, 1); ISSUE_B(3, 1); LOAD_A(5, s2); COMPUTE(0); WAITV(2); ENDPHASE();
    WRITE_A(4, s1, 0); ISSUE_B(4, 0); LOAD_A(6, s0); COMPUTE(1); WAITV(2); ENDPHASE();
    WRITE_A(5, s2, 1); ISSUE_B(5, 1); LOAD_A(7, s1); COMPUTE(0); WAITV(2); ENDPHASE();
    WRITE_A(6, s0, 0); ISSUE_B(6, 0); LOAD_A(8, s2); COMPUTE(1); WAITV(2); ENDPHASE();
    WRITE_A(7, s1, 1); ISSUE_B(7, 1); LOAD_A(9, s0); COMPUTE(0); WAITV(2); ENDPHASE();
    WRITE_A(8, s2, 0); ISSUE_B(8, 0);                COMPUTE(1); WAITV(0); ENDPHASE();
    WRITE_A(9, s0, 1); ISSUE_B(9, 1);                COMPUTE(0); WAITV(0); ENDPHASE();
    COMPUTE(1);

    // ---- epilogue: out[m][g] = acc + Vx'[i][g] + Vx'[j][g] (Ub folded in Vx') ----
    {
        const int mrow = m0 + w * 16 + r;
        int j = mrow % NN;
        int ti = mrow / NN;       // b*NN + i
        int b = ti / NN;
        const float* vi = Vx + (size_t)ti * HH;
        const float* vj = Vx + (size_t)(b * NN + j) * HH;
        float* orow = out + (size_t)mrow * HH;
        const int gbase = gh * (GHF * 16);
#pragma unroll
        for (int f = 0; f < GHF; ++f) {
            int g0 = gbase + f * 16 + q * 4;
            if (g0 + 4 <= HH) {
                float4v vi4 = *reinterpret_cast<const float4v*>(vi + g0);
                float4v vj4 = *reinterpret_cast<const float4v*>(vj + g0);
                *reinterpret_cast<float4v*>(orow + g0) = acc[f] + vi4 + vj4;
            }
        }
    }
#undef LOAD_A
#undef WRITE_A
#undef ISSUE_B
#undef COMPUTE
#undef WAITV
#undef ENDPHASE
}

extern "C" void kernel_launch(void* const* d_in, const int* in_sizes, int n_in,
                              void* d_out, int out_size, void* d_ws, size_t ws_size,
                              hipStream_t stream) {
    const float* x  = (const float*)d_in[0];
    const float* e  = (const float*)d_in[1];
    const float* Uw = (const float*)d_in[2];
    const float* Ub = (const float*)d_in[3];
    const float* Vw = (const float*)d_in[4];
    const float* Vb = (const float*)d_in[5];
    float* out = (float*)d_out;

    ushort* Bp = (ushort*)d_ws;                              // 204,800 B (frag-packed bf16 U_w)
    float*  Vx = (float*)((char*)d_ws + 204800);             // 960,000 B

    pack_u<<<50, 256, 0, stream>>>(Uw, Bp);
    vx_kernel<<<BB * NN, 256, 0, stream>>>(x, Vw, Vb, Ub, Vx);
    // 2500 m-tiles x 2 g-halves; twin blocks (same e rows) adjacent for L3 reuse
    gemm_kernel<<<5000, 256, 0, stream>>>(e, Bp, Vx, out);
}

// Round 11
// 149.904 us; speedup vs baseline: 1.2342x; 1.2342x over previous
//
#include <hip/hip_runtime.h>
#include <hip/hip_bf16.h>

#define BB 4
#define NN 200
#define HH 300
#define GF 20             // g-frags of 16 (G padded to 320; frag 19 zero)
#define BM 128            // rows per block
#define BCHUNK 40960      // B bytes per K-chunk (2 ks * 20 frags * 1024)

typedef __attribute__((ext_vector_type(8))) short short8;
typedef __attribute__((ext_vector_type(4))) float float4v;

static __device__ __forceinline__ ushort f2bf(float x) {
    union { float f; uint u; } v; v.f = x;
    uint r = v.u + 0x7FFFu + ((v.u >> 16) & 1u);  // RNE
    return (ushort)(r >> 16);
}

// 8 f32 -> 8 bf16 (RNE) via v_cvt_pk_bf16_f32
static __device__ __forceinline__ short8 pack8_cvt(float4v a, float4v b) {
    uint u0, u1, u2, u3;
    asm("v_cvt_pk_bf16_f32 %0, %1, %2" : "=v"(u0) : "v"(a[0]), "v"(a[1]));
    asm("v_cvt_pk_bf16_f32 %0, %1, %2" : "=v"(u1) : "v"(a[2]), "v"(a[3]));
    asm("v_cvt_pk_bf16_f32 %0, %1, %2" : "=v"(u2) : "v"(b[0]), "v"(b[1]));
    asm("v_cvt_pk_bf16_f32 %0, %1, %2" : "=v"(u3) : "v"(b[2]), "v"(b[3]));
    union { uint u[4]; short8 s; } r;
    r.u[0] = u0; r.u[1] = u1; r.u[2] = u2; r.u[3] = u3;
    return r.s;
}

static __device__ __forceinline__ void gload_lds16(const void* g, void* l) {
    __builtin_amdgcn_global_load_lds(
        (const __attribute__((address_space(1))) unsigned int*)g,
        (__attribute__((address_space(3))) unsigned int*)l, 16, 0, 0);
}

// Pack U_w (g,h) f32 -> bf16 in MFMA frag order (ks-major):
// Bp[((ks*GF+gf)*64 + lane)*8 + j] = Uw[g=gf*16+(lane&15)][h=ks*32+(lane>>4)*8+j], 0 if OOB
__global__ void pack_u(const float* __restrict__ Uw, ushort* __restrict__ Bp) {
    int idx = blockIdx.x * 256 + threadIdx.x;
    if (idx >= 10 * GF * 64) return;
    int lane = idx & 63;
    int kg = idx >> 6;
    int gf = kg % GF, ks = kg / GF;
    int g = gf * 16 + (lane & 15);
    int h0 = ks * 32 + (lane >> 4) * 8;
    ushort v[8];
#pragma unroll
    for (int j = 0; j < 8; ++j) {
        int h = h0 + j;
        v[j] = (g < HH && h < HH) ? f2bf(Uw[g * HH + h]) : (ushort)0;
    }
    *reinterpret_cast<short8*>(Bp + (size_t)idx * 8) = *reinterpret_cast<const short8*>(v);
}

// Vx[b,n,g] = sum_h x[b,n,h]*Vw[g,h] + Vb[g] + 0.5*Ub[g]   (Ub folded)
__global__ void vx_kernel(const float* __restrict__ x, const float* __restrict__ Vw,
                          const float* __restrict__ Vb, const float* __restrict__ Ub,
                          float* __restrict__ Vx) {
    __shared__ float xs[HH];
    int row = blockIdx.x;
    const float* xr = x + (size_t)row * HH;
    for (int h = threadIdx.x; h < HH; h += 256) xs[h] = xr[h];
    __syncthreads();
    for (int g = threadIdx.x; g < HH; g += 256) {
        const float4* wr = reinterpret_cast<const float4*>(Vw + (size_t)g * HH);
        const float4* xv = reinterpret_cast<const float4*>(xs);
        float s0 = 0.f, s1 = 0.f, s2 = 0.f, s3 = 0.f;
#pragma unroll 5
        for (int k = 0; k < HH / 4; ++k) {
            float4 w = wr[k];
            float4 xx = xv[k];
            s0 += w.x * xx.x; s1 += w.y * xx.y; s2 += w.z * xx.z; s3 += w.w * xx.w;
        }
        Vx[(size_t)row * HH + g] = Vb[g] + 0.5f * Ub[g] + s0 + s1 + s2 + s3;
    }
}

// R8 pipeline (BM=128 x full G, 512 thr, K in 5 chunks of 64, gload_lds staging,
// counted vmcnt, raw barriers) + NEW row-linear epilogue: acc bounced through
// per-wave LDS (reusing dead staging LDS), then contiguous 640-B reads/adds/stores.
__launch_bounds__(512, 2)
__global__ void gemm_kernel(const float* __restrict__ e, const ushort* __restrict__ Bp,
                            const float* __restrict__ Vx, float* __restrict__ out) {
    __shared__ __align__(16) char SMEM[147456];   // [0,64K): Af[2]; [64K,144K): Bf[2]
    const int tid = threadIdx.x;
    const int w = tid >> 6, l = tid & 63;
    const int r = l & 15, q = l >> 4;
    const int m0 = blockIdx.x * BM;

#define AFB(P_) (SMEM + (P_) * 32768)
#define BFB(P_) (SMEM + 65536 + (P_) * 40960)

#define WAITV(N_) asm volatile("s_waitcnt vmcnt(" #N_ ")" ::: "memory")
#define BAR() do {                                                   \
        __builtin_amdgcn_sched_barrier(0);                           \
        asm volatile("s_waitcnt lgkmcnt(0)" ::: "memory");           \
        __builtin_amdgcn_sched_barrier(0);                           \
        __builtin_amdgcn_s_barrier();                                \
        __builtin_amdgcn_sched_barrier(0);                           \
    } while (0)

    // A chunk stage: 4 rounds, each wave writes 1KB linear LDS (4 rows x 256B).
    // Global src permuted by the 16B-unit swizzle; k-tail (chunk 4) clamped.
#define STAGE_A(KC_, P_) do {                                                   \
        _Pragma("unroll")                                                       \
        for (int rd_ = 0; rd_ < 4; ++rd_) {                                     \
            int row_ = rd_ * 32 + w * 4 + (l >> 4);                             \
            int ucl_ = (l & 15) ^ (row_ & 15);                                  \
            const char* src_ = (const char*)(e + (size_t)(m0 + row_) * HH)      \
                               + (KC_) * 256 + ucl_ * 16;                       \
            if ((KC_) == 4 && ucl_ >= 11) src_ = (const char*)e;                \
            gload_lds16(src_, AFB(P_) + rd_ * 8192 + w * 1024 + l * 16);        \
        }                                                                       \
    } while (0)

    // B chunk stage: 5 rounds x 8KB, fully linear
#define STAGE_B(KC_, P_) do {                                                   \
        const char* bs_ = (const char*)Bp + (size_t)(KC_) * BCHUNK;             \
        char* bd_ = BFB(P_);                                                    \
        _Pragma("unroll")                                                       \
        for (int rd_ = 0; rd_ < 5; ++rd_)                                       \
            gload_lds16(bs_ + rd_ * 8192 + tid * 16, bd_ + rd_ * 8192 + tid * 16); \
    } while (0)

    float4v acc[GF];
#pragma unroll
    for (int f = 0; f < GF; ++f) acc[f] = (float4v){0.f, 0.f, 0.f, 0.f};

    // compute one chunk (2 sub-ks x 20 frags = 40 MFMA per wave)
#define COMPUTE(P_) do {                                                        \
        const char* ab_ = AFB(P_) + (w * 16 + r) * 256;                         \
        const ushort* bb_ = (const ushort*)BFB(P_);                             \
        _Pragma("unroll")                                                       \
        for (int s_ = 0; s_ < 2; ++s_) {                                        \
            int u0_ = (s_ * 8 + 2 * q) ^ r;                                     \
            int u1_ = (s_ * 8 + 2 * q + 1) ^ r;                                 \
            float4v fa0_ = *reinterpret_cast<const float4v*>(ab_ + u0_ * 16);   \
            float4v fa1_ = *reinterpret_cast<const float4v*>(ab_ + u1_ * 16);   \
            short8 fa_ = pack8_cvt(fa0_, fa1_);                                 \
            const ushort* bs_ = bb_ + s_ * (GF * 512) + l * 8;                  \
            _Pragma("unroll")                                                   \
            for (int f_ = 0; f_ < GF; ++f_) {                                   \
                short8 bfr_ = *reinterpret_cast<const short8*>(bs_ + f_ * 512); \
                acc[f_] = __builtin_amdgcn_mfma_f32_16x16x32_bf16(bfr_, fa_, acc[f_], 0, 0, 0); \
            }                                                                   \
        }                                                                       \
    } while (0)

    // ---- pipeline: 9 gloads/thread per chunk; counted vmcnt, never 0 mid-loop ----
    STAGE_A(0, 0); STAGE_B(0, 0);
    STAGE_A(1, 1); STAGE_B(1, 1);
    WAITV(9); BAR();

    COMPUTE(0); BAR();
    STAGE_A(2, 0); STAGE_B(2, 0); WAITV(9); BAR();

    COMPUTE(1); BAR();
    STAGE_A(3, 1); STAGE_B(3, 1); WAITV(9); BAR();

    COMPUTE(0); BAR();
    STAGE_A(4, 0); STAGE_B(4, 0); WAITV(9); BAR();

    COMPUTE(1); BAR();
    WAITV(0); BAR();

    COMPUTE(0);

    // ---- row-linear epilogue via per-wave LDS bounce ----
    // All waves done reading staging LDS before overlaying it:
    asm volatile("s_waitcnt lgkmcnt(0)" ::: "memory");
    __builtin_amdgcn_s_barrier();
    __builtin_amdgcn_sched_barrier(0);

    char* ep = SMEM + w * 10496;        // 16 rows x 656 B, wave-private
    const int mbase = m0 + w * 16;

#pragma unroll
    for (int gh2 = 0; gh2 < 2; ++gh2) {
        if (gh2) {  // round-0 reads must finish before overwriting the bounce tile
            asm volatile("s_waitcnt lgkmcnt(0)" ::: "memory");
            __builtin_amdgcn_sched_barrier(0);
        }
        // scatter acc -> LDS (lane (r,q) owns g = f*16 + q*4 .. +4 of row r)
#pragma unroll
        for (int ff = 0; ff < 10; ++ff) {
            int f = gh2 * 10 + ff;
            if (f < 19)
                *reinterpret_cast<float4v*>(ep + r * 656 + ff * 64 + q * 16) = acc[f];
        }
        asm volatile("s_waitcnt lgkmcnt(0)" ::: "memory");
        __builtin_amdgcn_sched_barrier(0);
        // stream rows: 640-B (gh0) / 560-B (gh1) contiguous read+add+store per row
        const int nl = gh2 ? 35 : 40;   // gh1: g = 160 + l*4 < 300
#pragma unroll 4
        for (int rr = 0; rr < 16; ++rr) {
            if (l < nl) {
                float4v v = *reinterpret_cast<const float4v*>(ep + rr * 656 + l * 16);
                int m = mbase + rr;
                int j = m % NN;
                int ti = m / NN;        // b*NN + i
                int b = ti / NN;
                int g0 = gh2 * 160 + l * 4;
                float4v vi4 = *reinterpret_cast<const float4v*>(Vx + (size_t)ti * HH + g0);
                float4v vj4 = *reinterpret_cast<const float4v*>(Vx + (size_t)(b * NN + j) * HH + g0);
                *reinterpret_cast<float4v*>(out + (size_t)m * HH + g0) = v + vi4 + vj4;
            }
        }
    }
#undef COMPUTE
#undef STAGE_A
#undef STAGE_B
#undef BAR
#undef WAITV
#undef AFB
#undef BFB
}

extern "C" void kernel_launch(void* const* d_in, const int* in_sizes, int n_in,
                              void* d_out, int out_size, void* d_ws, size_t ws_size,
                              hipStream_t stream) {
    const float* x  = (const float*)d_in[0];
    const float* e  = (const float*)d_in[1];
    const float* Uw = (const float*)d_in[2];
    const float* Ub = (const float*)d_in[3];
    const float* Vw = (const float*)d_in[4];
    const float* Vb = (const float*)d_in[5];
    float* out = (float*)d_out;

    ushort* Bp = (ushort*)d_ws;                              // 204,800 B (frag-packed bf16 U_w)
    float*  Vx = (float*)((char*)d_ws + 204800);             // 960,000 B

    pack_u<<<50, 256, 0, stream>>>(Uw, Bp);
    vx_kernel<<<BB * NN, 256, 0, stream>>>(x, Vw, Vb, Ub, Vx);
    gemm_kernel<<<160000 / BM, 512, 0, stream>>>(e, Bp, Vx, out);
}